// Round 6
// baseline (117.256 us; speedup 1.0000x reference)
//
#include <hip/hip_runtime.h>
#include <hip/hip_bf16.h>

typedef __attribute__((ext_vector_type(8))) short bf16x8;
typedef __attribute__((ext_vector_type(4))) float f32x4;
typedef __attribute__((ext_vector_type(2))) float f32x2;
typedef __attribute__((ext_vector_type(4))) int i32x4;
typedef __attribute__((ext_vector_type(4))) unsigned int u32x4;
typedef __attribute__((ext_vector_type(2))) unsigned int u32x2;

#define B_   8
#define C_   64
#define T_   32
#define N_   400
#define BT_  256
#define NKT_ 13
#define CN_  12800           /* T_*N_ = c-stride in x */
#define VROW 424             /* Vt row stride (bf16): mod32 words = 20 -> 2-way */
#define WROW 72              /* wvb row stride (bf16): mod32 words = 4 -> 2-way */
#define OBW  65              /* ob row stride (f32): mod32 = 1 -> conflict-free */
#define OBROWS 208           /* 13 itiles per store pass */
#define L2E_ 1.4426950408889634f
#define SH6_ (-8.656170245333780f)     /* -6 * log2(e) */

#if __has_builtin(__builtin_amdgcn_exp2f)
#define EXP2F(x) __builtin_amdgcn_exp2f(x)
#else
#define EXP2F(x) __expf((x) * 0.6931471805599453f)
#endif

// ---------------------------------------------------------------- prep: bit-pack gso
__global__ __launch_bounds__(256) void gat_prep(
    const int* __restrict__ gso, unsigned int* __restrict__ mb)
{
  int idx = blockIdx.x*256 + threadIdx.x;
  if (idx < N_*16) {
    int i = idx >> 4, kw = idx & 15;
    unsigned int bits = 0;
    if (kw < 13) {
      int j0 = kw * 32;
      #pragma unroll
      for (int bb = 0; bb < 32; ++bb) {
        int j = j0 + bb;
        if (j < N_ && gso[i*N_ + j] != 0) bits |= (1u << bb);
      }
    }
    mb[idx] = bits;
  }
}

// ---------------------------------------------------------------- fused kernel
// One block per bt (grid 256 = 1 block/CU).
// Phase 1: V-projection MFMA GEMM with 4 augmented score rows; epilogue
//   builds separable exp tables (exp(leaky(si+sd)-12)=max(E1i*e1d, E2i*e2d)).
// Phase 2 (SERIALIZATION RESTRUCTURE): each wave's task = one 16-row itile,
//   BOTH heads (6 accumulators) -> all 64 channels of a row live in-wave ->
//   LayerNorm fully in registers (4x shfl_xor), ob written once post-LN,
//   read once for the coalesced transposed store. 2 passes {13,12 itiles},
//   3 phase-2 barriers total (was 12); pass-B sweep overlaps pass-A store
//   drain. Masks/LUT shared across heads (halved traffic).
__global__ __launch_bounds__(1024) void gat_fused(
    const float* __restrict__ x, const float* __restrict__ Wq,
    const float* __restrict__ Wk, const float* __restrict__ Wv,
    const float* __restrict__ a_src, const float* __restrict__ a_dst,
    const float* __restrict__ gamma, const float* __restrict__ beta,
    const unsigned int* __restrict__ mb, float* __restrict__ out)
{
  __shared__ __align__(16) __hip_bfloat16 Vt[64][VROW];   // 54272 B
  __shared__ __align__(16) __hip_bfloat16 wvb[80][WROW];  // 11520 B
  __shared__ __align__(16) float e1d_s[2][416];           // 3328 B
  __shared__ __align__(16) float e2d_s[2][416];           // 3328 B
  __shared__ __align__(16) float si_s[2][400];            // 3200 B
  __shared__ __align__(16) float ob[OBROWS][OBW];         // 54080 B
  __shared__ __align__(16) unsigned int lut_s[16][2];     // 128 B
  __shared__ float g_s[64], b_s[64];                      // 512 B
  // total 130368 B (< 128 KiB)

  const int tid = threadIdx.x;
  const int bt = blockIdx.x;
  const int b = bt >> 5, t = bt & 31;
  const int lane = tid & 63, wave = tid >> 6;
  const int col = lane & 15, quad = lane >> 4;

  // ---- phase-1 prefetch: first tile's x loads issued before staging
  const float* xbase = x + ((size_t)b*C_*T_ + t)*N_;   // elem (c,n): xbase[c*CN_+n]
  float xf0[2][8];
  {
    const int n0 = wave*16;
    #pragma unroll
    for (int kt = 0; kt < 2; ++kt) {
      const float* xc = xbase + (size_t)(kt*32 + quad*8)*CN_ + n0 + col;
      #pragma unroll
      for (int j = 0; j < 8; ++j) xf0[kt][j] = xc[(size_t)j*CN_];
    }
  }

  // ---- phase 0: stage weights + LUT + zero pads
  #pragma unroll
  for (int it = 0; it < 4; ++it) {            // Wv rows 0..63 -> bf16
    int idx = it*1024 + tid;
    int o = idx >> 6, c = idx & 63;
    wvb[o][c] = __float2bfloat16(Wv[o*C_ + c]);
  }
  if (tid < 256) {                            // folded score rows 64..67 (xL2E)
    int ww = tid >> 6, c = tid & 63, h = ww >> 1;
    const float* W = (ww & 1) ? Wk : Wq;
    const float* a = (ww & 1) ? a_dst : a_src;
    float s = 0.f;
    #pragma unroll
    for (int d = 0; d < 32; ++d) s += W[(h*32 + d)*C_ + c] * a[h*32 + d];
    wvb[64 + ww][c] = __float2bfloat16(s * L2E_);
  } else if (tid < 320) {
    g_s[tid - 256] = gamma[tid - 256];
  } else if (tid < 384) {
    b_s[tid - 320] = beta[tid - 320];
  } else if (tid < 448) {                     // zero exp-table pads [400,416)
    int tt = tid - 384;
    int h = (tt >> 4) & 1, cc = 400 + (tt & 15);
    if (tt < 32) e1d_s[h][cc] = 0.f; else e2d_s[h][cc] = 0.f;
  } else if (tid < 464) {                     // nibble -> 2 pair-masks LUT
    int n = tid - 448;
    lut_s[n][0] = ((n & 1) ? 0x0000FFFFu : 0u) | ((n & 2) ? 0xFFFF0000u : 0u);
    lut_s[n][1] = ((n & 4) ? 0x0000FFFFu : 0u) | ((n & 8) ? 0xFFFF0000u : 0u);
  }
  for (int idx = tid; idx < 12*WROW; idx += 1024)   // zero wvb rows 68..79
    wvb[68 + idx/WROW][idx % WROW] = __float2bfloat16(0.f);
  for (int idx = tid; idx < 64*24; idx += 1024)     // zero Vt cols [400,424)
    Vt[idx/24][400 + idx%24] = __float2bfloat16(0.f);
  __syncthreads();

  // ---- phase 1: projection GEMM, tiles wave and wave+16 (25 total)
  {
    auto proj_tile = [&](int n0, const float xf[2][8]) {
      bf16x8 bfrag[2];
      #pragma unroll
      for (int kt = 0; kt < 2; ++kt) {
        union { short s[8]; bf16x8 v; } pk;
        #pragma unroll
        for (int j = 0; j < 8; ++j) {
          union { __hip_bfloat16 h; short s; } cv;
          cv.h = __float2bfloat16(xf[kt][j]);
          pk.s[j] = cv.s;
        }
        bfrag[kt] = pk.v;
      }
      #pragma unroll
      for (int ot = 0; ot < 5; ++ot) {
        f32x4 acc = {0.f, 0.f, 0.f, 0.f};
        #pragma unroll
        for (int kt = 0; kt < 2; ++kt) {
          bf16x8 afr = *(const bf16x8*)&wvb[ot*16 + col][kt*32 + quad*8];
          acc = __builtin_amdgcn_mfma_f32_16x16x32_bf16(afr, bfrag[kt], acc, 0, 0, 0);
        }
        if (ot < 4) {
          #pragma unroll
          for (int r = 0; r < 4; ++r)
            Vt[ot*16 + quad*4 + r][n0 + col] = __float2bfloat16(acc[r]);
        } else if (quad == 0) {               // rows 64..67 = score types
          #pragma unroll
          for (int r = 0; r < 4; ++r) {
            int h = r >> 1;
            if (r & 1) {                      // dst scores -> exp tables
              e1d_s[h][n0 + col] = EXP2F(acc[r] + SH6_);
              e2d_s[h][n0 + col] = EXP2F(fmaf(0.2f, acc[r], SH6_));
            } else {                          // src scores kept linear (xL2E)
              si_s[h][n0 + col] = acc[r];
            }
          }
        }
      }
    };

    proj_tile(wave*16, xf0);
    if (wave < 9) {
      float xf1[2][8];
      const int n0 = (wave + 16)*16;
      #pragma unroll
      for (int kt = 0; kt < 2; ++kt) {
        const float* xc = xbase + (size_t)(kt*32 + quad*8)*CN_ + n0 + col;
        #pragma unroll
        for (int j = 0; j < 8; ++j) xf1[kt][j] = xc[(size_t)j*CN_];
      }
      proj_tile(n0, xf1);
    }
  }
  __syncthreads();

  // ---- phase 2: both-heads-per-wave tasks, in-register LN, 2 passes
  const int rowA = col;
  const unsigned int qsh = quad * 8;

  bf16x8 ones;
  #pragma unroll
  for (int k = 0; k < 8; ++k) ones[k] = (short)0x3F80;

  // gamma/beta for this lane's 4 channel slots (c = a2*16 + col)
  float gr0 = g_s[col],      gr1 = g_s[16 + col],
        gr2 = g_s[32 + col], gr3 = g_s[48 + col];
  float br0 = b_s[col],      br1 = b_s[16 + col],
        br2 = b_s[32 + col], br3 = b_s[48 + col];

  const float* e1p0 = e1d_s[0] + quad*8;
  const float* e2p0 = e2d_s[0] + quad*8;
  const float* e1p1 = e1d_s[1] + quad*8;
  const float* e2p1 = e2d_s[1] + quad*8;
  const __hip_bfloat16* v00p = &Vt[rowA][quad*8];        // h0, d 0..15
  const __hip_bfloat16* v01p = v00p + 16*VROW;           // h0, d 16..31
  const __hip_bfloat16* v10p = &Vt[32 + rowA][quad*8];   // h1, d 0..15
  const __hip_bfloat16* v11p = v10p + 16*VROW;           // h1, d 16..31

  struct Res { f32x4 a00, a01, a10, a11, s0, s1; };

  auto sweep = [&](int itile) -> Res {
    const int irow = itile*16 + rowA;
    const float si0 = si_s[0][irow];
    const float si1 = si_s[1][irow];
    const float E10s = EXP2F(si0 + SH6_), E20s = EXP2F(fmaf(0.2f, si0, SH6_));
    const float E11s = EXP2F(si1 + SH6_), E21s = EXP2F(fmaf(0.2f, si1, SH6_));
    const f32x2 e1A = {E10s, E10s}, e2A = {E20s, E20s};
    const f32x2 e1B = {E11s, E11s}, e2B = {E21s, E21s};

    const u32x4* mp = (const u32x4*)(mb + irow*16);
    u32x4 mw0 = mp[0], mw1 = mp[1], mw2 = mp[2];
    unsigned int mw12 = mb[irow*16 + 12];

    Res R;
    R.a00 = (f32x4){0,0,0,0}; R.a01 = (f32x4){0,0,0,0};
    R.a10 = (f32x4){0,0,0,0}; R.a11 = (f32x4){0,0,0,0};
    R.s0  = (f32x4){0,0,0,0}; R.s1  = (f32x4){0,0,0,0};

    #pragma unroll
    for (int kt = 0; kt < NKT_; ++kt) {
      unsigned int mword = (kt < 4) ? mw0[kt] : (kt < 8) ? mw1[kt-4]
                         : (kt < 12) ? mw2[kt-8] : mw12;
      unsigned int mbyte = (mword >> qsh) & 0xffu;
      u32x2 mlo = *(const u32x2*)&lut_s[mbyte & 15u][0];
      u32x2 mhi = *(const u32x2*)&lut_s[mbyte >> 4][0];

      // ---- head 0
      {
        union { f32x4 v4[2]; f32x2 v2[4]; } u1, u2;
        u1.v4[0] = *(const f32x4*)(e1p0 + kt*32);
        u1.v4[1] = *(const f32x4*)(e1p0 + kt*32 + 4);
        u2.v4[0] = *(const f32x4*)(e2p0 + kt*32);
        u2.v4[1] = *(const f32x4*)(e2p0 + kt*32 + 4);
        bf16x8 vb0 = *(const bf16x8*)(v00p + kt*32);
        bf16x8 vb1 = *(const bf16x8*)(v01p + kt*32);
        u32x2 w[4];
        #pragma unroll
        for (int q2 = 0; q2 < 4; ++q2) {
          f32x2 a = e1A * u1.v2[q2];          // v_pk_mul_f32
          f32x2 c = e2A * u2.v2[q2];
          f32x2 m = {fmaxf(a.x, c.x), fmaxf(a.y, c.y)};
          union { f32x2 f; u32x2 u; } cvt; cvt.f = m;
          w[q2] = cvt.u;
        }
        union { i32x4 i; bf16x8 v; } af;
        af.i.x = (int)(__builtin_amdgcn_perm(w[0].y, w[0].x, 0x07060302u) & mlo.x);
        af.i.y = (int)(__builtin_amdgcn_perm(w[1].y, w[1].x, 0x07060302u) & mlo.y);
        af.i.z = (int)(__builtin_amdgcn_perm(w[2].y, w[2].x, 0x07060302u) & mhi.x);
        af.i.w = (int)(__builtin_amdgcn_perm(w[3].y, w[3].x, 0x07060302u) & mhi.y);
        R.a00 = __builtin_amdgcn_mfma_f32_16x16x32_bf16(af.v, vb0, R.a00, 0, 0, 0);
        R.a01 = __builtin_amdgcn_mfma_f32_16x16x32_bf16(af.v, vb1, R.a01, 0, 0, 0);
        R.s0  = __builtin_amdgcn_mfma_f32_16x16x32_bf16(af.v, ones, R.s0, 0, 0, 0);
      }
      // ---- head 1
      {
        union { f32x4 v4[2]; f32x2 v2[4]; } u1, u2;
        u1.v4[0] = *(const f32x4*)(e1p1 + kt*32);
        u1.v4[1] = *(const f32x4*)(e1p1 + kt*32 + 4);
        u2.v4[0] = *(const f32x4*)(e2p1 + kt*32);
        u2.v4[1] = *(const f32x4*)(e2p1 + kt*32 + 4);
        bf16x8 vb0 = *(const bf16x8*)(v10p + kt*32);
        bf16x8 vb1 = *(const bf16x8*)(v11p + kt*32);
        u32x2 w[4];
        #pragma unroll
        for (int q2 = 0; q2 < 4; ++q2) {
          f32x2 a = e1B * u1.v2[q2];
          f32x2 c = e2B * u2.v2[q2];
          f32x2 m = {fmaxf(a.x, c.x), fmaxf(a.y, c.y)};
          union { f32x2 f; u32x2 u; } cvt; cvt.f = m;
          w[q2] = cvt.u;
        }
        union { i32x4 i; bf16x8 v; } af;
        af.i.x = (int)(__builtin_amdgcn_perm(w[0].y, w[0].x, 0x07060302u) & mlo.x);
        af.i.y = (int)(__builtin_amdgcn_perm(w[1].y, w[1].x, 0x07060302u) & mlo.y);
        af.i.z = (int)(__builtin_amdgcn_perm(w[2].y, w[2].x, 0x07060302u) & mhi.x);
        af.i.w = (int)(__builtin_amdgcn_perm(w[3].y, w[3].x, 0x07060302u) & mhi.y);
        R.a10 = __builtin_amdgcn_mfma_f32_16x16x32_bf16(af.v, vb0, R.a10, 0, 0, 0);
        R.a11 = __builtin_amdgcn_mfma_f32_16x16x32_bf16(af.v, vb1, R.a11, 0, 0, 0);
        R.s1  = __builtin_amdgcn_mfma_f32_16x16x32_bf16(af.v, ones, R.s1, 0, 0, 0);
      }
    }
    return R;
  };

  // in-register LayerNorm + transposed ds_write (ob row rl, channels a2*16+col)
  auto write_ln = [&](const Res& R, int itile, int r0pass) {
    #pragma unroll
    for (int r = 0; r < 4; ++r) {
      float li0 = 1.0f / R.s0[r];
      float li1 = 1.0f / R.s1[r];
      float v0 = R.a00[r] * li0;
      float v1 = R.a01[r] * li0;
      float v2 = R.a10[r] * li1;
      float v3 = R.a11[r] * li1;
      float s = v0 + v1 + v2 + v3;
      s += __shfl_xor(s, 1); s += __shfl_xor(s, 2);
      s += __shfl_xor(s, 4); s += __shfl_xor(s, 8);
      float mu = s * (1.f/64.f);
      float d0v = v0 - mu, d1v = v1 - mu, d2v = v2 - mu, d3v = v3 - mu;
      float q = d0v*d0v; q = fmaf(d1v, d1v, q);
      q = fmaf(d2v, d2v, q); q = fmaf(d3v, d3v, q);
      q += __shfl_xor(q, 1); q += __shfl_xor(q, 2);
      q += __shfl_xor(q, 4); q += __shfl_xor(q, 8);
      float rstd = rsqrtf(q*(1.f/64.f) + 1e-5f);
      int rl = itile*16 - r0pass + quad*4 + r;
      ob[rl][     col] = d0v*rstd*gr0 + br0;
      ob[rl][16 + col] = d1v*rstd*gr1 + br1;
      ob[rl][32 + col] = d2v*rstd*gr2 + br2;
      ob[rl][48 + col] = d3v*rstd*gr3 + br3;
    }
  };

  // coalesced transposed store: n-contiguous lanes, c wave-uniform
  auto store_rows = [&](int r0, int rows) {
    for (int rr = 0; rr < rows; rr += 128) {
      #pragma unroll
      for (int it = 0; it < 8; ++it) {
        int idx = it*1024 + tid;
        int c = idx >> 7, nn = idx & 127;
        int rl = rr + nn;
        if (rl < rows)
          out[((size_t)(b*C_ + c)*T_ + t)*N_ + r0 + rl] = ob[rl][c];
      }
    }
  };

  // pass A: itiles 0..12 (rows 0..207)
  Res RA;
  if (wave < 13) { RA = sweep(wave); write_ln(RA, wave, 0); }
  __syncthreads();                 // ob[A] complete
  store_rows(0, OBROWS);           // global stores issued
  // pass B sweep overlaps store-A drain (doesn't touch ob)
  Res RB;
  if (wave < 12) RB = sweep(13 + wave);
  __syncthreads();                 // store-A ds_reads complete
  if (wave < 12) write_ln(RB, 13 + wave, OBROWS);
  __syncthreads();                 // ob[B] complete
  store_rows(OBROWS, N_ - OBROWS);
}

// ---------------------------------------------------------------- launch
extern "C" void kernel_launch(void* const* d_in, const int* in_sizes, int n_in,
                              void* d_out, int out_size, void* d_ws, size_t ws_size,
                              hipStream_t stream) {
  (void)in_sizes; (void)n_in; (void)out_size; (void)ws_size;
  const float* x     = (const float*)d_in[0];
  const float* Wq    = (const float*)d_in[1];
  const float* Wk    = (const float*)d_in[2];
  const float* Wv    = (const float*)d_in[3];
  const float* a_src = (const float*)d_in[4];
  const float* a_dst = (const float*)d_in[5];
  const float* gamma = (const float*)d_in[6];
  const float* beta  = (const float*)d_in[7];
  const int*   gso   = (const int*)d_in[8];
  float* out = (float*)d_out;

  unsigned int* mbp = (unsigned int*)d_ws;   // 400*16 u32 = 25600 B

  gat_prep<<<26, 256, 0, stream>>>(gso, mbp);
  gat_fused<<<BT_, 1024, 0, stream>>>(x, Wq, Wk, Wv, a_src, a_dst,
                                      gamma, beta, mbp, out);
}

// Round 7
// 116.463 us; speedup vs baseline: 1.0068x; 1.0068x over previous
//
#include <hip/hip_runtime.h>
#include <hip/hip_bf16.h>

typedef __attribute__((ext_vector_type(8))) short bf16x8;
typedef __attribute__((ext_vector_type(4))) float f32x4;
typedef __attribute__((ext_vector_type(4))) int i32x4;
typedef __attribute__((ext_vector_type(4))) unsigned int u32x4;
typedef __attribute__((ext_vector_type(2))) unsigned int u32x2;

#define B_   8
#define C_   64
#define T_   32
#define N_   400
#define BT_  256
#define NKT_ 13
#define CN_  12800           /* T_*N_ = c-stride in x */
#define VROW 424             /* Vt row stride (bf16): 212 words, mod32=20 -> 2-way */
#define WROW 72              /* wvb row stride (bf16): 36 words, mod32=4 -> 2-way */
#define L2E_ 1.4426950408889634f
#define SH6_ (-8.656170245333780f)     /* -6 * log2(e) */

#if __has_builtin(__builtin_amdgcn_exp2f)
#define EXP2F(x) __builtin_amdgcn_exp2f(x)
#else
#define EXP2F(x) __expf((x) * 0.6931471805599453f)
#endif

// Barrier that drains ONLY the LDS counter (lgkmcnt), not vmcnt.
// Every cross-wave dependency in this kernel is through LDS; global
// stores/loads in flight are never a cross-wave hazard here. Avoids the
// vmcnt(0) drain __syncthreads() would impose after each store pass.
#define BARRIER() asm volatile("s_waitcnt lgkmcnt(0)\n\ts_barrier" ::: "memory")

// ---------------------------------------------------------------- prep: bit-pack gso
// (round-0/2 layout: 16 u32 words per row, 25600 B workspace — known-safe size)
__global__ __launch_bounds__(256) void gat_prep(
    const int* __restrict__ gso, unsigned int* __restrict__ mb)
{
  int idx = blockIdx.x*256 + threadIdx.x;
  if (idx < N_*16) {
    int i = idx >> 4, kw = idx & 15;
    unsigned int bits = 0;
    if (kw < 13) {
      int j0 = kw * 32;
      #pragma unroll
      for (int bb = 0; bb < 32; ++bb) {
        int j = j0 + bb;
        if (j < N_ && gso[i*N_ + j] != 0) bits |= (1u << bb);
      }
    }
    mb[idx] = bits;
  }
}

// ---------------------------------------------------------------- fused kernel
// One block per bt (grid 256 = 1 block/CU). Round-2 structure (best measured:
// 115.6 µs harness) with lgkm-only barriers. Phase 1: V-projection MFMA GEMM
// with 4 augmented score rows; epilogue builds separable exp tables
// (exp(leaky(si+sd)-12) = max(E1i*e1d[j], E2i*e2d[j])). Phase 2: per-128-row
// pass: transcendental-free register softmax (mul,mul,max + LDS nibble-LUT
// mask) -> MFMA P*V (+ones row-sum) -> LDS LN -> transposed store.
__global__ __launch_bounds__(1024) void gat_fused(
    const float* __restrict__ x, const float* __restrict__ Wq,
    const float* __restrict__ Wk, const float* __restrict__ Wv,
    const float* __restrict__ a_src, const float* __restrict__ a_dst,
    const float* __restrict__ gamma, const float* __restrict__ beta,
    const unsigned int* __restrict__ mb, float* __restrict__ out)
{
  __shared__ __align__(16) __hip_bfloat16 Vt[64][VROW];   // 54272 B
  __shared__ __align__(16) __hip_bfloat16 wvb[80][WROW];  // 11520 B
  __shared__ __align__(16) float e1d_s[2][416];           // 3328 B
  __shared__ __align__(16) float e2d_s[2][416];           // 3328 B
  __shared__ __align__(16) float si_s[2][400];            // 3200 B
  __shared__ __align__(16) float ob[128][68];             // 34816 B
  __shared__ __align__(16) unsigned int lut_s[16][2];     // 128 B
  __shared__ float g_s[64], b_s[64];                      // 512 B

  const int tid = threadIdx.x;
  const int bt = blockIdx.x;
  const int b = bt >> 5, t = bt & 31;
  const int lane = tid & 63, wave = tid >> 6;
  const int col = lane & 15, quad = lane >> 4;

  // ---- phase 0: stage weights + LUT + zero pads
  #pragma unroll
  for (int it = 0; it < 4; ++it) {            // Wv rows 0..63 -> bf16
    int idx = it*1024 + tid;
    int o = idx >> 6, c = idx & 63;
    wvb[o][c] = __float2bfloat16(Wv[o*C_ + c]);
  }
  if (tid < 256) {                            // folded score rows 64..67 (xL2E)
    int ww = tid >> 6, c = tid & 63, h = ww >> 1;
    const float* W = (ww & 1) ? Wk : Wq;
    const float* a = (ww & 1) ? a_dst : a_src;
    float s = 0.f;
    #pragma unroll
    for (int d = 0; d < 32; ++d) s += W[(h*32 + d)*C_ + c] * a[h*32 + d];
    wvb[64 + ww][c] = __float2bfloat16(s * L2E_);
  } else if (tid < 320) {
    g_s[tid - 256] = gamma[tid - 256];
  } else if (tid < 384) {
    b_s[tid - 320] = beta[tid - 320];
  } else if (tid < 448) {                     // zero exp-table pads [400,416)
    int tt = tid - 384;
    int h = (tt >> 4) & 1, cc = 400 + (tt & 15);
    if (tt < 32) e1d_s[h][cc] = 0.f; else e2d_s[h][cc] = 0.f;
  } else if (tid < 464) {                     // nibble -> 2 pair-masks LUT
    int n = tid - 448;
    lut_s[n][0] = ((n & 1) ? 0x0000FFFFu : 0u) | ((n & 2) ? 0xFFFF0000u : 0u);
    lut_s[n][1] = ((n & 4) ? 0x0000FFFFu : 0u) | ((n & 8) ? 0xFFFF0000u : 0u);
  }
  for (int idx = tid; idx < 12*WROW; idx += 1024)   // zero wvb rows 68..79
    wvb[68 + idx/WROW][idx % WROW] = __float2bfloat16(0.f);
  for (int idx = tid; idx < 64*24; idx += 1024)     // zero Vt cols [400,424)
    Vt[idx/24][400 + idx%24] = __float2bfloat16(0.f);
  BARRIER();

  // ---- phase 1: projection GEMM, 25 n-tile tasks over 16 waves
  {
    const float* xbase = x + ((size_t)b*C_*T_ + t)*N_;   // elem (c,n): xbase[c*CN_+n]
    for (int nt = wave; nt < 25; nt += 16) {
      const int n0 = nt*16;
      bf16x8 bfrag[2];
      #pragma unroll
      for (int kt = 0; kt < 2; ++kt) {        // B[k=c][col=n] from global
        const float* xc = xbase + (size_t)(kt*32 + quad*8)*CN_ + n0 + col;
        union { short s[8]; bf16x8 v; } pk;
        #pragma unroll
        for (int j = 0; j < 8; ++j) {
          union { __hip_bfloat16 h; short s; } cv;
          cv.h = __float2bfloat16(xc[(size_t)j*CN_]);
          pk.s[j] = cv.s;
        }
        bfrag[kt] = pk.v;
      }
      #pragma unroll
      for (int ot = 0; ot < 5; ++ot) {
        f32x4 acc = {0.f, 0.f, 0.f, 0.f};
        #pragma unroll
        for (int kt = 0; kt < 2; ++kt) {
          bf16x8 afr = *(const bf16x8*)&wvb[ot*16 + col][kt*32 + quad*8];
          acc = __builtin_amdgcn_mfma_f32_16x16x32_bf16(afr, bfrag[kt], acc, 0, 0, 0);
        }
        // D: col(lane&15) = n - n0, row quad*4+r = o - ot*16
        if (ot < 4) {
          #pragma unroll
          for (int r = 0; r < 4; ++r)
            Vt[ot*16 + quad*4 + r][n0 + col] = __float2bfloat16(acc[r]);
        } else if (quad == 0) {               // rows 64..67 = score types
          #pragma unroll
          for (int r = 0; r < 4; ++r) {
            int h = r >> 1;
            if (r & 1) {                      // dst scores -> exp tables
              e1d_s[h][n0 + col] = EXP2F(acc[r] + SH6_);
              e2d_s[h][n0 + col] = EXP2F(fmaf(0.2f, acc[r], SH6_));
            } else {                          // src scores kept linear (xL2E)
              si_s[h][n0 + col] = acc[r];
            }
          }
        }
      }
    }
  }
  BARRIER();

  // ---- phase 2: attention + LN + store, 128 rows per pass
  const int hh = wave & 1, itile = wave >> 1;      // 2 heads x 8 itiles
  const int rowA = col;
  const unsigned int qsh = quad * 8;

  bf16x8 ones;
  #pragma unroll
  for (int k = 0; k < 8; ++k) ones[k] = (short)0x3F80;

  for (int r0 = 0; r0 < N_; r0 += 128) {
    const int ibase = r0 + itile*16;
    if (ibase < N_) {
      const int irow = ibase + rowA;
      const float si1 = si_s[hh][irow];
      const float E1i = EXP2F(si1 + SH6_);
      const float E2i = EXP2F(fmaf(0.2f, si1, SH6_));
      const u32x4* mp = (const u32x4*)(mb + irow*16);
      u32x4 mw0 = mp[0], mw1 = mp[1], mw2 = mp[2];
      unsigned int mw12 = mb[irow*16 + 12];
      const float* e1p = e1d_s[hh] + quad*8;
      const float* e2p = e2d_s[hh] + quad*8;
      const __hip_bfloat16* v0p = &Vt[hh*32 + rowA][quad*8];
      const __hip_bfloat16* v1p = v0p + 16*VROW;

      f32x4 d0 = {0,0,0,0}, d1 = {0,0,0,0}, d2 = {0,0,0,0};
      #pragma unroll
      for (int kt = 0; kt < NKT_; ++kt) {
        unsigned int mword = (kt < 4) ? mw0[kt] : (kt < 8) ? mw1[kt-4]
                           : (kt < 12) ? mw2[kt-8] : mw12;
        unsigned int mbyte = (mword >> qsh) & 0xffu;
        u32x2 mlo = *(const u32x2*)&lut_s[mbyte & 15u][0];
        u32x2 mhi = *(const u32x2*)&lut_s[mbyte >> 4][0];
        f32x4 x1a = *(const f32x4*)(e1p + kt*32);
        f32x4 x1b = *(const f32x4*)(e1p + kt*32 + 4);
        f32x4 x2a = *(const f32x4*)(e2p + kt*32);
        f32x4 x2b = *(const f32x4*)(e2p + kt*32 + 4);
        bf16x8 vb0 = *(const bf16x8*)(v0p + kt*32);
        bf16x8 vb1 = *(const bf16x8*)(v1p + kt*32);
        unsigned int eu[8];
        #pragma unroll
        for (int jj = 0; jj < 8; ++jj) {
          float f1 = (jj < 4) ? x1a[jj] : x1b[jj-4];
          float f2 = (jj < 4) ? x2a[jj] : x2b[jj-4];
          // exp(leaky(si+sd)-12) = max(E1i*exp(sd-6), E2i*exp(.2sd-6))
          eu[jj] = __float_as_uint(fmaxf(E1i * f1, E2i * f2));
        }
        union { i32x4 i; bf16x8 v; } af;
        af.i.x = (int)(__builtin_amdgcn_perm(eu[1], eu[0], 0x07060302u) & mlo.x);
        af.i.y = (int)(__builtin_amdgcn_perm(eu[3], eu[2], 0x07060302u) & mlo.y);
        af.i.z = (int)(__builtin_amdgcn_perm(eu[5], eu[4], 0x07060302u) & mhi.x);
        af.i.w = (int)(__builtin_amdgcn_perm(eu[7], eu[6], 0x07060302u) & mhi.y);
        d0 = __builtin_amdgcn_mfma_f32_16x16x32_bf16(af.v, vb0, d0, 0, 0, 0);
        d1 = __builtin_amdgcn_mfma_f32_16x16x32_bf16(af.v, vb1, d1, 0, 0, 0);
        d2 = __builtin_amdgcn_mfma_f32_16x16x32_bf16(af.v, ones, d2, 0, 0, 0);
      }
      #pragma unroll
      for (int r = 0; r < 4; ++r) {
        float li = 1.0f / d2[r];
        int rl = itile*16 + quad*4 + r;
        ob[rl][hh*32 + rowA]      = d0[r] * li;
        ob[rl][hh*32 + 16 + rowA] = d1[r] * li;
      }
    }
    BARRIER();

    { // fused LayerNorm over C=64 (8 lanes per row)
      int rl = tid >> 3, cgi = tid & 7;
      int n = r0 + rl;
      if (n < N_) {
        float u[8]; float s = 0.f;
        #pragma unroll
        for (int k = 0; k < 8; ++k) { u[k] = ob[rl][cgi*8 + k]; s += u[k]; }
        s += __shfl_xor(s,1); s += __shfl_xor(s,2); s += __shfl_xor(s,4);
        float mu = s * (1.f/64.f);
        float q = 0.f;
        #pragma unroll
        for (int k = 0; k < 8; ++k) { float dv = u[k]-mu; q = fmaf(dv,dv,q); }
        q += __shfl_xor(q,1); q += __shfl_xor(q,2); q += __shfl_xor(q,4);
        float rstd = rsqrtf(q*(1.f/64.f) + 1e-5f);
        #pragma unroll
        for (int k = 0; k < 8; ++k)
          ob[rl][cgi*8 + k] = (u[k]-mu)*rstd*g_s[cgi*8 + k] + b_s[cgi*8 + k];
      }
    }
    BARRIER();

    // transposed store to (B,C,T,N): c wave-uniform, n-contiguous lanes
    #pragma unroll
    for (int it = 0; it < 8; ++it) {
      int idx = it*1024 + tid;
      int c = idx >> 7, nn = idx & 127;
      int n = r0 + nn;
      if (n < N_) out[((size_t)(b*C_ + c)*T_ + t)*N_ + n] = ob[nn][c];
    }
    BARRIER();
  }
}

// ---------------------------------------------------------------- launch
extern "C" void kernel_launch(void* const* d_in, const int* in_sizes, int n_in,
                              void* d_out, int out_size, void* d_ws, size_t ws_size,
                              hipStream_t stream) {
  (void)in_sizes; (void)n_in; (void)out_size; (void)ws_size;
  const float* x     = (const float*)d_in[0];
  const float* Wq    = (const float*)d_in[1];
  const float* Wk    = (const float*)d_in[2];
  const float* Wv    = (const float*)d_in[3];
  const float* a_src = (const float*)d_in[4];
  const float* a_dst = (const float*)d_in[5];
  const float* gamma = (const float*)d_in[6];
  const float* beta  = (const float*)d_in[7];
  const int*   gso   = (const int*)d_in[8];
  float* out = (float*)d_out;

  unsigned int* mbp = (unsigned int*)d_ws;   // 400*16 u32 = 25600 B

  gat_prep<<<26, 256, 0, stream>>>(gso, mbp);
  gat_fused<<<BT_, 1024, 0, stream>>>(x, Wq, Wk, Wv, a_src, a_dst,
                                      gamma, beta, mbp, out);
}